// Round 9
// baseline (66.742 us; speedup 1.0000x reference)
//
#include <hip/hip_runtime.h>
#include <hip/hip_fp16.h>

#define NN 1536      // n_nodes
#define FDIM 32      // p == fts == 32
#define TG 96        // GEMM tile (grid 16x16x2 = 512 blocks = 2/CU)
#define KS 32        // K-step (one mfma_16x16x32 worth of K)
#define NTH 24       // K-tiles per split-K half (1536/2/32)

typedef __attribute__((ext_vector_type(8))) __bf16 bf16x8;
typedef __attribute__((ext_vector_type(4))) float f32x4;
typedef _Float16 h16x2 __attribute__((ext_vector_type(2)));

typedef __attribute__((address_space(3))) unsigned char as3_u8;
typedef __attribute__((address_space(1))) unsigned char as1_u8;

__device__ __forceinline__ void gload_lds16(const void* g, void* l) {
    __builtin_amdgcn_global_load_lds((const as1_u8*)g, (as3_u8*)l, 16, 0, 0);
}

// ---------------------------------------------------------------------------
// Split A into bf16 hi/lo AND zero d_out (replaces the 43us rocclr fill:
// same element count, one float4 of zeros per thread).
// ---------------------------------------------------------------------------
__device__ __forceinline__ unsigned short bf16rne(float f) {
    unsigned u = __float_as_uint(f);
    return (unsigned short)((u + 0x7FFFu + ((u >> 16) & 1u)) >> 16);
}

__global__ __launch_bounds__(256) void gud_split(const float* __restrict__ A,
                                                 unsigned short* __restrict__ Ah,
                                                 unsigned short* __restrict__ Al,
                                                 float* __restrict__ outz) {
    int gid = blockIdx.x * 256 + threadIdx.x;      // 4 floats per thread
    float4 v = reinterpret_cast<const float4*>(A)[gid];
    ushort4 h, l;
    float x;
    x = v.x; h.x = bf16rne(x); l.x = bf16rne(x - __uint_as_float((unsigned)h.x << 16));
    x = v.y; h.y = bf16rne(x); l.y = bf16rne(x - __uint_as_float((unsigned)h.y << 16));
    x = v.z; h.z = bf16rne(x); l.z = bf16rne(x - __uint_as_float((unsigned)h.z << 16));
    x = v.w; h.w = bf16rne(x); l.w = bf16rne(x - __uint_as_float((unsigned)h.w << 16));
    reinterpret_cast<ushort4*>(Ah)[gid] = h;
    reinterpret_cast<ushort4*>(Al)[gid] = l;
    reinterpret_cast<float4*>(outz)[gid] = (float4){0.f, 0.f, 0.f, 0.f};
}

// ---------------------------------------------------------------------------
// Prep: Q_l = P @ W1[l] for l = 1,2.  f16 outputs:
// QIh[i][l*32+f] = f16(Q + b1),  RJh[j][l*32+f] = f16(-Q).
// ---------------------------------------------------------------------------
__global__ __launch_bounds__(256) void gud_prep(const float* __restrict__ P,
                                                const float* __restrict__ W1,
                                                const float* __restrict__ b1,
                                                _Float16* __restrict__ QIh,
                                                _Float16* __restrict__ RJh) {
    int gid = blockIdx.x * 256 + threadIdx.x;   // 0 .. NN*64-1
    int i  = gid >> 6;
    int lf = gid & 63;
    int l  = (lf >> 5) + 1;   // 1 or 2
    int f  = lf & 31;
    const float* prow = P + i * FDIM;
    const float* w    = W1 + l * FDIM * FDIM + f;
    float q = 0.f;
#pragma unroll
    for (int c = 0; c < FDIM; ++c) q = fmaf(prow[c], w[c * FDIM], q);
    QIh[i * 64 + lf] = (_Float16)(q + b1[l * FDIM + f]);
    RJh[i * 64 + lf] = (_Float16)(-q);
}

// ---------------------------------------------------------------------------
// Split-K MFMA GEMM: blockIdx.z = K-half. acc = A*A over this half via bf16
// hi/lo (AhBh + AlBh + AhBl). Partials atomicAdd'ed into zeroed d_out —
// exactly 2 commutative addends per element => deterministic.
// 3 LDS buffers, 2-deep prefetch, counted vmcnt(6). 2 blocks/CU co-resident.
// ---------------------------------------------------------------------------
__global__ __launch_bounds__(256, 2) void gud_gemm(
        const unsigned short* __restrict__ Ah,
        const unsigned short* __restrict__ Al,
        float* __restrict__ out) {
    __shared__ char smem[3 * 24576];   // 73728 B

    const int tid  = threadIdx.x;
    const int lane = tid & 63;
    const int w    = tid >> 6;          // wave 0..3
    const int wr   = w >> 1, wc = w & 1;
    const int i0   = blockIdx.y * TG;
    const int j0   = blockIdx.x * TG;
    const int kh   = blockIdx.z;        // K-half 0/1
    const int kbase = kh * (NN / 2) * 2;   // byte offset of this half's columns

    // ---- staging: wave w owns subtile w (0=Ah@i0, 1=Al@i0, 2=Ah@j0, 3=Al@j0)
    const unsigned short* src = (w & 1) ? Al : Ah;
    const int rowbase = (w < 2) ? i0 : j0;
    int goffs[6];
#pragma unroll
    for (int s = 0; s < 6; ++s) {
        int rt    = 16 * s + (lane >> 2);          // row within tile 0..95
        int chunk = (lane & 3) ^ ((rt >> 1) & 3);  // inverse swizzle on source
        goffs[s]  = (rowbase + rt) * (NN * 2) + kbase + chunk * 16;
    }

    // ---- fragment read offsets (swizzled); rows of 64B = K=32 bf16
    int aoff[3], boff[3];
    const int kb = lane >> 4;
#pragma unroll
    for (int m = 0; m < 3; ++m) {
        int ra  = wr * 48 + m * 16 + (lane & 15);
        aoff[m] = ra * 64 + ((kb ^ ((ra >> 1) & 3)) * 16);
        int rb  = wc * 48 + m * 16 + (lane & 15);
        boff[m] = rb * 64 + ((kb ^ ((rb >> 1) & 3)) * 16);
    }

    f32x4 acc[3][3];
#pragma unroll
    for (int m = 0; m < 3; ++m)
#pragma unroll
        for (int n = 0; n < 3; ++n) acc[m][n] = (f32x4){0.f, 0.f, 0.f, 0.f};

    auto compute = [&](const char* buf) {
        bf16x8 ahf[3], alf[3], bhf[3], blf[3];
#pragma unroll
        for (int m = 0; m < 3; ++m) {
            ahf[m] = *(const bf16x8*)(buf + 0     + aoff[m]);
            alf[m] = *(const bf16x8*)(buf + 6144  + aoff[m]);
            bhf[m] = *(const bf16x8*)(buf + 12288 + boff[m]);
            blf[m] = *(const bf16x8*)(buf + 18432 + boff[m]);
        }
#pragma unroll
        for (int m = 0; m < 3; ++m)
#pragma unroll
            for (int n = 0; n < 3; ++n) {
                acc[m][n] = __builtin_amdgcn_mfma_f32_16x16x32_bf16(ahf[m], bhf[n], acc[m][n], 0, 0, 0);
                acc[m][n] = __builtin_amdgcn_mfma_f32_16x16x32_bf16(alf[m], bhf[n], acc[m][n], 0, 0, 0);
                acc[m][n] = __builtin_amdgcn_mfma_f32_16x16x32_bf16(ahf[m], blf[n], acc[m][n], 0, 0, 0);
            }
    };

    // ---- prologue: stage k-tiles 0,1 into buffers 0,1
#pragma unroll
    for (int s = 0; s < 6; ++s)
        gload_lds16((const char*)src + goffs[s], smem + w * 6144 + s * 1024);
#pragma unroll
    for (int s = 0; s < 6; ++s)
        gload_lds16((const char*)src + goffs[s] + 64, smem + 24576 + w * 6144 + s * 1024);

    // ---- main loop: counted vmcnt(6) keeps next tile's 6 loads in flight
    for (int kt = 0; kt < NTH - 1; ++kt) {
        asm volatile("s_waitcnt vmcnt(6)" ::: "memory");
        __builtin_amdgcn_s_barrier();
        if (kt + 2 < NTH) {   // stage kt+2 AFTER barrier (its buffer is free)
            char* dst = smem + ((kt + 2) % 3) * 24576 + w * 6144;
            const int kbyte = (kt + 2) * (KS * 2);
#pragma unroll
            for (int s = 0; s < 6; ++s)
                gload_lds16((const char*)src + goffs[s] + kbyte, dst + s * 1024);
        }
        compute(smem + (kt % 3) * 24576);
    }
    asm volatile("s_waitcnt vmcnt(0)" ::: "memory");
    __builtin_amdgcn_s_barrier();
    compute(smem + ((NTH - 1) % 3) * 24576);

    // ---- epilogue: atomic-accumulate partial A^2 into d_out
    const int crow = (lane >> 4) * 4;
    const int ccol = lane & 15;
#pragma unroll
    for (int m = 0; m < 3; ++m)
#pragma unroll
        for (int n = 0; n < 3; ++n) {
            const int ib = i0 + wr * 48 + m * 16 + crow;
            const int jb = j0 + wc * 48 + n * 16 + ccol;
#pragma unroll
            for (int r = 0; r < 4; ++r)
                atomicAdd(&out[(size_t)(ib + r) * NN + jb], acc[m][n][r]);
        }
}

// ---------------------------------------------------------------------------
// Conv pass, in place on io (= A^2 in, conv out):
//   io[i,j] = A[i,j]*(m1+bb1) + io[i,j]*(m2+bb2) + (i==j)*c0
// 1152 blocks: 8 i-rows (QI tile in LDS, broadcast reads) x 256 j (RJ in
// registers). f16 packed math: pk_add + pk_max + v_dot2_f32_f16.
// ---------------------------------------------------------------------------
__global__ __launch_bounds__(256) void gud_conv(
        const float* __restrict__ A,
        float* io,
        const _Float16* __restrict__ QIh,
        const _Float16* __restrict__ RJh,
        const float* __restrict__ b1,
        const float* __restrict__ W2,
        const float* __restrict__ b2) {
    __shared__ uint4 QIs[64];          // 8 rows x 128 B

    const int tid = threadIdx.x;
    const int j   = blockIdx.x * 256 + tid;
    const int i0  = blockIdx.y * 8;

    if (tid < 64) {
        int row = tid >> 3, c = tid & 7;
        QIs[tid] = ((const uint4*)(QIh + (size_t)(i0 + row) * 64))[c];
    }

    uint4 rj4[8];
#pragma unroll
    for (int c = 0; c < 8; ++c)
        rj4[c] = ((const uint4*)(RJh + (size_t)j * 64))[c];
    const unsigned* rw = (const unsigned*)rj4;

    // W2 layers 1,2 concat (feature f -> W2[32+f]) as f16 pairs
    h16x2 w2h[32];
#pragma unroll
    for (int k = 0; k < 32; ++k) {
        h16x2 t; t.x = (_Float16)W2[32 + 2 * k]; t.y = (_Float16)W2[33 + 2 * k];
        w2h[k] = t;
    }
    float c0 = b2[0];
#pragma unroll
    for (int f = 0; f < FDIM; ++f) c0 = fmaf(fmaxf(b1[f], 0.f), W2[f], c0);
    const float bb1 = b2[1], bb2 = b2[2];
    const h16x2 z = {(_Float16)0, (_Float16)0};

    __syncthreads();

#pragma unroll
    for (int ii = 0; ii < 8; ++ii) {
        uint4 q4[8];
#pragma unroll
        for (int c = 0; c < 8; ++c) q4[c] = QIs[ii * 8 + c];
        const unsigned* qw = (const unsigned*)q4;

        float m1 = 0.f, m2 = 0.f;
#pragma unroll
        for (int k = 0; k < 16; ++k) {
            h16x2 h = __builtin_bit_cast(h16x2, qw[k]) + __builtin_bit_cast(h16x2, rw[k]);
            h = __builtin_elementwise_max(h, z);
            m1 = __builtin_amdgcn_fdot2(h, w2h[k], m1, false);
        }
#pragma unroll
        for (int k = 16; k < 32; ++k) {
            h16x2 h = __builtin_bit_cast(h16x2, qw[k]) + __builtin_bit_cast(h16x2, rw[k]);
            h = __builtin_elementwise_max(h, z);
            m2 = __builtin_amdgcn_fdot2(h, w2h[k], m2, false);
        }

        const size_t off = (size_t)(i0 + ii) * NN + j;
        float v = A[off] * (m1 + bb1) + io[off] * (m2 + bb2);
        if (i0 + ii == j) v += c0;
        io[off] = v;
    }
}

// ---------------------------------------------------------------------------
extern "C" void kernel_launch(void* const* d_in, const int* in_sizes, int n_in,
                              void* d_out, int out_size, void* d_ws, size_t ws_size,
                              hipStream_t stream) {
    const float* A  = (const float*)d_in[0];   // [NN,NN] A_norm (symmetric)
    const float* P  = (const float*)d_in[1];   // [NN,32]
    const float* W1 = (const float*)d_in[2];   // [3,32,32]
    const float* b1 = (const float*)d_in[3];   // [3,32]
    const float* W2 = (const float*)d_in[4];   // [3,32,1]
    const float* b2 = (const float*)d_in[5];   // [3,1]
    float* out = (float*)d_out;

    unsigned short* Ahh = (unsigned short*)d_ws;                 // NN*NN bf16
    unsigned short* All = Ahh + (size_t)NN * NN;                 // NN*NN bf16
    _Float16* QIh = (_Float16*)(All + (size_t)NN * NN);          // NN*64 f16
    _Float16* RJh = QIh + (size_t)NN * 64;                       // NN*64 f16

    gud_split<<<dim3(NN * NN / 1024), 256, 0, stream>>>(A, Ahh, All, out);
    gud_prep<<<dim3(NN * 64 / 256), 256, 0, stream>>>(P, W1, b1, QIh, RJh);
    gud_gemm<<<dim3(NN / TG, NN / TG, 2), 256, 0, stream>>>(Ahh, All, out);
    gud_conv<<<dim3(NN / 256, NN / 8), 256, 0, stream>>>(A, out, QIh, RJh,
                                                         b1, W2, b2);
}

// Round 10
// 53.657 us; speedup vs baseline: 1.2439x; 1.2439x over previous
//
#include <hip/hip_runtime.h>
#include <hip/hip_fp16.h>

#define NN 1536      // n_nodes
#define FDIM 32      // p == fts == 32
#define TG 96        // GEMM tile (grid 16x16x2 = 512 blocks = 2/CU)
#define KS 32        // K-step (one mfma_16x16x32 worth of K)
#define NTH 24       // K-tiles per split-K half (1536/2/32)

typedef __attribute__((ext_vector_type(8))) __bf16 bf16x8;
typedef __attribute__((ext_vector_type(4))) float f32x4;
typedef _Float16 h16x2 __attribute__((ext_vector_type(2)));

typedef __attribute__((address_space(3))) unsigned char as3_u8;
typedef __attribute__((address_space(1))) unsigned char as1_u8;

__device__ __forceinline__ void gload_lds16(const void* g, void* l) {
    __builtin_amdgcn_global_load_lds((const as1_u8*)g, (as3_u8*)l, 16, 0, 0);
}

// ---------------------------------------------------------------------------
// Split A into bf16 hi/lo: Ah = rne_bf16(a), Al = rne_bf16(a - float(Ah)).
// ---------------------------------------------------------------------------
__device__ __forceinline__ unsigned short bf16rne(float f) {
    unsigned u = __float_as_uint(f);
    return (unsigned short)((u + 0x7FFFu + ((u >> 16) & 1u)) >> 16);
}

__global__ __launch_bounds__(256) void gud_split(const float* __restrict__ A,
                                                 unsigned short* __restrict__ Ah,
                                                 unsigned short* __restrict__ Al) {
    int gid = blockIdx.x * 256 + threadIdx.x;      // 4 floats per thread
    float4 v = reinterpret_cast<const float4*>(A)[gid];
    ushort4 h, l;
    float x;
    x = v.x; h.x = bf16rne(x); l.x = bf16rne(x - __uint_as_float((unsigned)h.x << 16));
    x = v.y; h.y = bf16rne(x); l.y = bf16rne(x - __uint_as_float((unsigned)h.y << 16));
    x = v.z; h.z = bf16rne(x); l.z = bf16rne(x - __uint_as_float((unsigned)h.z << 16));
    x = v.w; h.w = bf16rne(x); l.w = bf16rne(x - __uint_as_float((unsigned)h.w << 16));
    reinterpret_cast<ushort4*>(Ah)[gid] = h;
    reinterpret_cast<ushort4*>(Al)[gid] = l;
}

// ---------------------------------------------------------------------------
// Prep: Q_l = P @ W1[l] for l = 1,2.  f16 outputs:
// QIh[i][l*32+f] = f16(Q + b1),  RJh[j][l*32+f] = f16(-Q).
// ---------------------------------------------------------------------------
__global__ __launch_bounds__(256) void gud_prep(const float* __restrict__ P,
                                                const float* __restrict__ W1,
                                                const float* __restrict__ b1,
                                                _Float16* __restrict__ QIh,
                                                _Float16* __restrict__ RJh) {
    int gid = blockIdx.x * 256 + threadIdx.x;   // 0 .. NN*64-1
    int i  = gid >> 6;
    int lf = gid & 63;
    int l  = (lf >> 5) + 1;   // 1 or 2
    int f  = lf & 31;
    const float* prow = P + i * FDIM;
    const float* w    = W1 + l * FDIM * FDIM + f;
    float q = 0.f;
#pragma unroll
    for (int c = 0; c < FDIM; ++c) q = fmaf(prow[c], w[c * FDIM], q);
    QIh[i * 64 + lf] = (_Float16)(q + b1[l * FDIM + f]);
    RJh[i * 64 + lf] = (_Float16)(-q);
}

// ---------------------------------------------------------------------------
// Split-K MFMA GEMM: blockIdx.z = K-half. acc = A*A over this half via bf16
// hi/lo (AhBh + AlBh + AhBl). Each half writes its OWN partial buffer with
// plain coalesced stores (round 9's atomicAdd caused cross-XCD cache-line
// ping-pong: two concurrent blocks per (i,j), same lines -> ~40us).
// 3 LDS buffers, 2-deep prefetch, counted vmcnt(6). 2 blocks/CU co-resident.
// ---------------------------------------------------------------------------
__global__ __launch_bounds__(256, 2) void gud_gemm(
        const unsigned short* __restrict__ Ah,
        const unsigned short* __restrict__ Al,
        float* __restrict__ Pk) {
    __shared__ char smem[3 * 24576];   // 73728 B

    const int tid  = threadIdx.x;
    const int lane = tid & 63;
    const int w    = tid >> 6;          // wave 0..3
    const int wr   = w >> 1, wc = w & 1;
    const int i0   = blockIdx.y * TG;
    const int j0   = blockIdx.x * TG;
    const int kh   = blockIdx.z;        // K-half 0/1
    const int kbase = kh * (NN / 2) * 2;   // byte offset of this half's columns

    // ---- staging: wave w owns subtile w (0=Ah@i0, 1=Al@i0, 2=Ah@j0, 3=Al@j0)
    const unsigned short* src = (w & 1) ? Al : Ah;
    const int rowbase = (w < 2) ? i0 : j0;
    int goffs[6];
#pragma unroll
    for (int s = 0; s < 6; ++s) {
        int rt    = 16 * s + (lane >> 2);          // row within tile 0..95
        int chunk = (lane & 3) ^ ((rt >> 1) & 3);  // inverse swizzle on source
        goffs[s]  = (rowbase + rt) * (NN * 2) + kbase + chunk * 16;
    }

    // ---- fragment read offsets (swizzled); rows of 64B = K=32 bf16
    int aoff[3], boff[3];
    const int kb = lane >> 4;
#pragma unroll
    for (int m = 0; m < 3; ++m) {
        int ra  = wr * 48 + m * 16 + (lane & 15);
        aoff[m] = ra * 64 + ((kb ^ ((ra >> 1) & 3)) * 16);
        int rb  = wc * 48 + m * 16 + (lane & 15);
        boff[m] = rb * 64 + ((kb ^ ((rb >> 1) & 3)) * 16);
    }

    f32x4 acc[3][3];
#pragma unroll
    for (int m = 0; m < 3; ++m)
#pragma unroll
        for (int n = 0; n < 3; ++n) acc[m][n] = (f32x4){0.f, 0.f, 0.f, 0.f};

    auto compute = [&](const char* buf) {
        bf16x8 ahf[3], alf[3], bhf[3], blf[3];
#pragma unroll
        for (int m = 0; m < 3; ++m) {
            ahf[m] = *(const bf16x8*)(buf + 0     + aoff[m]);
            alf[m] = *(const bf16x8*)(buf + 6144  + aoff[m]);
            bhf[m] = *(const bf16x8*)(buf + 12288 + boff[m]);
            blf[m] = *(const bf16x8*)(buf + 18432 + boff[m]);
        }
#pragma unroll
        for (int m = 0; m < 3; ++m)
#pragma unroll
            for (int n = 0; n < 3; ++n) {
                acc[m][n] = __builtin_amdgcn_mfma_f32_16x16x32_bf16(ahf[m], bhf[n], acc[m][n], 0, 0, 0);
                acc[m][n] = __builtin_amdgcn_mfma_f32_16x16x32_bf16(alf[m], bhf[n], acc[m][n], 0, 0, 0);
                acc[m][n] = __builtin_amdgcn_mfma_f32_16x16x32_bf16(ahf[m], blf[n], acc[m][n], 0, 0, 0);
            }
    };

    // ---- prologue: stage k-tiles 0,1 into buffers 0,1
#pragma unroll
    for (int s = 0; s < 6; ++s)
        gload_lds16((const char*)src + goffs[s], smem + w * 6144 + s * 1024);
#pragma unroll
    for (int s = 0; s < 6; ++s)
        gload_lds16((const char*)src + goffs[s] + 64, smem + 24576 + w * 6144 + s * 1024);

    // ---- main loop: counted vmcnt(6) keeps next tile's 6 loads in flight
    for (int kt = 0; kt < NTH - 1; ++kt) {
        asm volatile("s_waitcnt vmcnt(6)" ::: "memory");
        __builtin_amdgcn_s_barrier();
        if (kt + 2 < NTH) {   // stage kt+2 AFTER barrier (its buffer is free)
            char* dst = smem + ((kt + 2) % 3) * 24576 + w * 6144;
            const int kbyte = (kt + 2) * (KS * 2);
#pragma unroll
            for (int s = 0; s < 6; ++s)
                gload_lds16((const char*)src + goffs[s] + kbyte, dst + s * 1024);
        }
        compute(smem + (kt % 3) * 24576);
    }
    asm volatile("s_waitcnt vmcnt(0)" ::: "memory");
    __builtin_amdgcn_s_barrier();
    compute(smem + ((NTH - 1) % 3) * 24576);

    // ---- epilogue: plain coalesced stores to this half's partial buffer
    float* dst = Pk + (size_t)kh * NN * NN;
    const int crow = (lane >> 4) * 4;
    const int ccol = lane & 15;
#pragma unroll
    for (int m = 0; m < 3; ++m)
#pragma unroll
        for (int n = 0; n < 3; ++n) {
            const int ib = i0 + wr * 48 + m * 16 + crow;
            const int jb = j0 + wc * 48 + n * 16 + ccol;
#pragma unroll
            for (int r = 0; r < 4; ++r)
                dst[(size_t)(ib + r) * NN + jb] = acc[m][n][r];
        }
}

// ---------------------------------------------------------------------------
// Conv pass: out[i,j] = A[i,j]*(m1+bb1) + (P0+P1)[i,j]*(m2+bb2) + (i==j)*c0
// 1152 blocks: 8 i-rows (QI tile in LDS, broadcast reads) x 256 j (RJ in
// registers). f16 packed math: pk_add + pk_max + v_dot2_f32_f16.
// ---------------------------------------------------------------------------
__global__ __launch_bounds__(256) void gud_conv(
        const float* __restrict__ A,
        const float* __restrict__ Pk,
        const _Float16* __restrict__ QIh,
        const _Float16* __restrict__ RJh,
        const float* __restrict__ b1,
        const float* __restrict__ W2,
        const float* __restrict__ b2,
        float* __restrict__ out) {
    __shared__ uint4 QIs[64];          // 8 rows x 128 B

    const int tid = threadIdx.x;
    const int j   = blockIdx.x * 256 + tid;
    const int i0  = blockIdx.y * 8;

    if (tid < 64) {
        int row = tid >> 3, c = tid & 7;
        QIs[tid] = ((const uint4*)(QIh + (size_t)(i0 + row) * 64))[c];
    }

    uint4 rj4[8];
#pragma unroll
    for (int c = 0; c < 8; ++c)
        rj4[c] = ((const uint4*)(RJh + (size_t)j * 64))[c];
    const unsigned* rw = (const unsigned*)rj4;

    // W2 layers 1,2 concat (feature f -> W2[32+f]) as f16 pairs
    h16x2 w2h[32];
#pragma unroll
    for (int k = 0; k < 32; ++k) {
        h16x2 t; t.x = (_Float16)W2[32 + 2 * k]; t.y = (_Float16)W2[33 + 2 * k];
        w2h[k] = t;
    }
    float c0 = b2[0];
#pragma unroll
    for (int f = 0; f < FDIM; ++f) c0 = fmaf(fmaxf(b1[f], 0.f), W2[f], c0);
    const float bb1 = b2[1], bb2 = b2[2];
    const h16x2 z = {(_Float16)0, (_Float16)0};

    const float* P0 = Pk;
    const float* P1 = Pk + (size_t)NN * NN;

    __syncthreads();

#pragma unroll
    for (int ii = 0; ii < 8; ++ii) {
        uint4 q4[8];
#pragma unroll
        for (int c = 0; c < 8; ++c) q4[c] = QIs[ii * 8 + c];
        const unsigned* qw = (const unsigned*)q4;

        float m1 = 0.f, m2 = 0.f;
#pragma unroll
        for (int k = 0; k < 16; ++k) {
            h16x2 h = __builtin_bit_cast(h16x2, qw[k]) + __builtin_bit_cast(h16x2, rw[k]);
            h = __builtin_elementwise_max(h, z);
            m1 = __builtin_amdgcn_fdot2(h, w2h[k], m1, false);
        }
#pragma unroll
        for (int k = 16; k < 32; ++k) {
            h16x2 h = __builtin_bit_cast(h16x2, qw[k]) + __builtin_bit_cast(h16x2, rw[k]);
            h = __builtin_elementwise_max(h, z);
            m2 = __builtin_amdgcn_fdot2(h, w2h[k], m2, false);
        }

        const size_t off = (size_t)(i0 + ii) * NN + j;
        float a2 = P0[off] + P1[off];
        float v = A[off] * (m1 + bb1) + a2 * (m2 + bb2);
        if (i0 + ii == j) v += c0;
        out[off] = v;
    }
}

// ---------------------------------------------------------------------------
extern "C" void kernel_launch(void* const* d_in, const int* in_sizes, int n_in,
                              void* d_out, int out_size, void* d_ws, size_t ws_size,
                              hipStream_t stream) {
    const float* A  = (const float*)d_in[0];   // [NN,NN] A_norm (symmetric)
    const float* P  = (const float*)d_in[1];   // [NN,32]
    const float* W1 = (const float*)d_in[2];   // [3,32,32]
    const float* b1 = (const float*)d_in[3];   // [3,32]
    const float* W2 = (const float*)d_in[4];   // [3,32,1]
    const float* b2 = (const float*)d_in[5];   // [3,1]
    float* out = (float*)d_out;

    float* Pk = (float*)d_ws;                                    // 2 x NN*NN f32
    unsigned short* Ahh = (unsigned short*)(Pk + 2 * (size_t)NN * NN);  // NN*NN bf16
    unsigned short* All = Ahh + (size_t)NN * NN;                 // NN*NN bf16
    _Float16* QIh = (_Float16*)(All + (size_t)NN * NN);          // NN*64 f16
    _Float16* RJh = QIh + (size_t)NN * 64;                       // NN*64 f16

    gud_split<<<dim3(NN * NN / 1024), 256, 0, stream>>>(A, Ahh, All);
    gud_prep<<<dim3(NN * 64 / 256), 256, 0, stream>>>(P, W1, b1, QIh, RJh);
    gud_gemm<<<dim3(NN / TG, NN / TG, 2), 256, 0, stream>>>(Ahh, All, Pk);
    gud_conv<<<dim3(NN / 256, NN / 8), 256, 0, stream>>>(A, Pk, QIh, RJh,
                                                         b1, W2, b2, out);
}